// Round 2
// baseline (354.556 us; speedup 1.0000x reference)
//
#include <hip/hip_runtime.h>

// Problem constants (from reference)
#define C_FIELDS 12
#define F_FIELDS 4
#define SLOTS    16      // C + F
#define D_DIM    128

using f32x4 = __attribute__((ext_vector_type(4))) float;

// One WAVE (64 lanes) per token.
//
//  - `token` is wave-uniform; we pin it to an SGPR with readfirstlane so the
//    12 cat indices (48 contiguous bytes) and 4 cont scalars (16 B) compile
//    to SCALAR loads (s_load via the constant cache), issued once at wave
//    start, off the per-lane vector-memory critical path. No __shfl needed.
//  - each lane owns 8 float4 chunks: iteration k covers rows {2k, 2k+1}
//    (lanes 0-31 -> row 2k, lanes 32-63 -> row 2k+1). k=0..5 are the 12
//    gather rows, k=6..7 the 4 cont rows -- compile-time split, no
//    divergence. All 6 table gathers (plus the 4 wc/bc vector loads) are
//    issued back-to-back before any use -> MLP ~= 10 per lane. The old
//    (356 us) kernel had MLP=1 with a dependent idx->gather chain per chunk;
//    the 268 MB write roofline is ~43 us, so it was latency-bound, not
//    BW-bound.
//  - per-lane gather address = cndmask(hi, sgpr_idx_even, sgpr_idx_odd) +
//    compile-time field offset: 2 VALU ops per gather, no LDS traffic.
//  - stores: per iteration the wave writes 2 adjacent rows = 1 KB
//    contiguous; nontemporal so the 268 MB write-once stream doesn't evict
//    the ~70 MB gather table from L2/L3.
__global__ __launch_bounds__(256) void emb_fused_kernel(
    const int*   __restrict__ cat,     // [NTOK, 12] int32
    const float* __restrict__ cont,    // [NTOK, 4]
    const float* __restrict__ table,   // [V_TOTAL, 128]
    const float* __restrict__ wc,      // [4, 128]
    const float* __restrict__ bc,      // [4, 128]
    float*       __restrict__ out,     // [NTOK*16, 128]
    int n_tok)
{
    const int gtid  = blockIdx.x * blockDim.x + threadIdx.x;
    int token = gtid >> 6;                       // one wave per token
    if (token >= n_tok) return;
    // Wave-uniform by construction (64-aligned waves); make it provably
    // uniform so the index/cont loads scalarize to s_load.
    token = __builtin_amdgcn_readfirstlane(token);

    const int lane = threadIdx.x & 63;
    const int hi   = lane >> 5;                  // which of the 2 rows per iter
    const int seg  = lane & 31;                  // float4 chunk within row
    const int d0   = seg << 2;                   // fp32 element offset in D

    // Exclusive prefix sums of VOCABS {100000,800,200,5000,60,30000,10,8,50,2000,20,16}
    constexpr int OFFS[C_FIELDS] = {
        0, 100000, 100800, 101000, 106000, 106060,
        136060, 136070, 136078, 136128, 138128, 138148
    };

    // --- wave-uniform scalar loads: 12 indices + 4 cont values ---
    const int*   catrow  = cat  + token * C_FIELDS;
    const float* controw = cont + token * F_FIELDS;
    int sidx[C_FIELDS];
#pragma unroll
    for (int c = 0; c < C_FIELDS; ++c) sidx[c] = catrow[c];
    float sx[F_FIELDS];
#pragma unroll
    for (int f = 0; f < F_FIELDS; ++f) sx[f] = controw[f];

    // --- per-lane gather addresses for rows 0..11 (6 per lane) ---
    int idxs[6];
    const float* ptrs[6];
#pragma unroll
    for (int k = 0; k < 6; ++k) {
        const int idx = hi ? sidx[2 * k + 1] : sidx[2 * k];   // v_cndmask
        const int off = hi ? OFFS[2 * k + 1] : OFFS[2 * k];
        idxs[k] = idx;
        ptrs[k] = table + (size_t)(off + idx) * D_DIM + d0;
    }

    // --- issue all 6 independent table gathers ---
    f32x4 v[6];
#pragma unroll
    for (int k = 0; k < 6; ++k) {
        v[k] = *reinterpret_cast<const f32x4*>(ptrs[k]);
    }

    // --- cont rows 12..15 (k=6,7): x * w_f + b_f ---
    f32x4 rc[2];
#pragma unroll
    for (int k = 0; k < 2; ++k) {
        const int   f = 2 * k + hi;              // field 0..3
        const float x = hi ? sx[2 * k + 1] : sx[2 * k];
        const f32x4 wv = *reinterpret_cast<const f32x4*>(wc + f * D_DIM + d0);
        const f32x4 bv = *reinterpret_cast<const f32x4*>(bc + f * D_DIM + d0);
        rc[k].x = fmaf(x, wv.x, bv.x);
        rc[k].y = fmaf(x, wv.y, bv.y);
        rc[k].z = fmaf(x, wv.z, bv.z);
        rc[k].w = fmaf(x, wv.w, bv.w);
    }

    // --- padding_idx: row 0 of each field is zero (idx uniform per half-wave) ---
#pragma unroll
    for (int k = 0; k < 6; ++k) {
        const f32x4 z = {0.f, 0.f, 0.f, 0.f};
        v[k] = (idxs[k] == 0) ? z : v[k];
    }

    // --- 8 nontemporal stores; wave writes 8 KB contiguous per token ---
    float* out_tok = out + (size_t)token * (SLOTS * D_DIM);
#pragma unroll
    for (int k = 0; k < 6; ++k) {
        __builtin_nontemporal_store(
            v[k], reinterpret_cast<f32x4*>(out_tok + (2 * k + hi) * D_DIM + d0));
    }
#pragma unroll
    for (int k = 0; k < 2; ++k) {
        __builtin_nontemporal_store(
            rc[k], reinterpret_cast<f32x4*>(out_tok + (12 + 2 * k + hi) * D_DIM + d0));
    }
}

extern "C" void kernel_launch(void* const* d_in, const int* in_sizes, int n_in,
                              void* d_out, int out_size, void* d_ws, size_t ws_size,
                              hipStream_t stream) {
    const int*   cat   = (const int*)d_in[0];
    const float* cont  = (const float*)d_in[1];
    const float* table = (const float*)d_in[2];
    const float* wc    = (const float*)d_in[3];
    const float* bc    = (const float*)d_in[4];
    float*       out   = (float*)d_out;

    const int n_tok = in_sizes[0] / C_FIELDS;    // B*L = 32768 (element count)
    const long long total_threads = (long long)n_tok * 64;  // one wave/token
    const int block = 256;
    const int grid  = (int)((total_threads + block - 1) / block);

    emb_fused_kernel<<<grid, block, 0, stream>>>(cat, cont, table, wc, bc, out, n_tok);
}

// Round 3
// 351.430 us; speedup vs baseline: 1.0089x; 1.0089x over previous
//
#include <hip/hip_runtime.h>

// Problem constants (from reference)
#define C_FIELDS 12
#define F_FIELDS 4
#define SLOTS    16      // C + F
#define D_DIM    128

using f32x4 = __attribute__((ext_vector_type(4))) float;

// One WAVE per token, PERSISTENT waves (grid = 2048 blocks = 32 waves/CU
// exactly), 4 tokens per wave at NTOK=32768.
//
// Evidence from R2 profile: the harness re-poisons 1.07 GB at ~170 us per
// iteration (fills at 6.26 TB/s are the top dispatches; our kernel is below
// them). The poison flushes L3 (256 MB) every iteration, so the 70 MB table
// is COLD each run; within-run reuse (~7x on ~29 MB of unique rows) must be
// captured by L2/L3 during the run -> NT stores on the 268 MB write-once
// output stream stay (they keep the table resident).
//
// This version targets the kernel's remaining latency/occupancy gap:
//  - u32 gather offsets from the SGPR table base (table is 70 MB < 4 GB):
//    no 64-bit per-lane pointer arrays -> VGPR ~55, safely under the
//    64-VGPR cliff -> 8 waves/SIMD.
//  - scalar (SALU) row math: per-slot row offsets and padding flags are
//    computed in SGPRs; per-lane work is 1 cndmask + 1 add per gather.
//  - persistent loop: the NEXT token's 12 indices + 4 cont scalars are
//    scalar-prefetched while the CURRENT token's 6 gathers are in flight,
//    hiding the s_load -> gather dependent chain.
//  - wc/bc (cont-field weights) hoisted out of the loop: loaded once per
//    wave instead of once per token.
//  - padding_idx: multiply by {0,1} mask (table values are finite), 1 VALU
//    for the mask select + 4 v_mul per gather row.
__global__ __launch_bounds__(256) void emb_fused_kernel(
    const int*   __restrict__ cat,     // [NTOK, 12] int32
    const float* __restrict__ cont,    // [NTOK, 4]
    const float* __restrict__ table,   // [V_TOTAL, 128]
    const float* __restrict__ wc,      // [4, 128]
    const float* __restrict__ bc,      // [4, 128]
    float*       __restrict__ out,     // [NTOK*16, 128]
    int n_tok)
{
    // Exclusive prefix sums of VOCABS {100000,800,200,5000,60,30000,10,8,50,2000,20,16}
    constexpr int OFFS[C_FIELDS] = {
        0, 100000, 100800, 101000, 106000, 106060,
        136060, 136070, 136078, 136128, 138128, 138148
    };

    const int lane = threadIdx.x & 63;
    const int hi   = lane >> 5;                  // row parity within pair
    const int d0   = (lane & 31) << 2;           // fp32 element offset in D

    // wave id is uniform by construction; pin to SGPR so all per-token
    // index/cont loads scalarize to s_load.
    const int wave0  = __builtin_amdgcn_readfirstlane(
        (int)((blockIdx.x * blockDim.x + threadIdx.x) >> 6));
    const int nwaves = (int)((gridDim.x * blockDim.x) >> 6);

    // --- loop-invariant cont-field weights: rows 12+2k+hi use field 2k+hi ---
    f32x4 wv[2], bv[2];
#pragma unroll
    for (int k = 0; k < 2; ++k) {
        const int f = 2 * k + hi;
        wv[k] = *reinterpret_cast<const f32x4*>(wc + f * D_DIM + d0);
        bv[k] = *reinterpret_cast<const f32x4*>(bc + f * D_DIM + d0);
    }

    int   sidx[C_FIELDS];
    float sx[F_FIELDS];
    auto load_scalars = [&](int token) {
        const int*   catrow  = cat  + token * C_FIELDS;   // uniform -> s_load
        const float* controw = cont + token * F_FIELDS;
#pragma unroll
        for (int c = 0; c < C_FIELDS; ++c) sidx[c] = catrow[c];
#pragma unroll
        for (int f = 0; f < F_FIELDS; ++f) sx[f] = controw[f];
    };

    int token = wave0;
    if (token >= n_tok) return;
    load_scalars(token);

    while (true) {
        // per-lane gather offsets (fp32-element units) + padding masks
        uint32_t voff[6];
        float    fmask[6];
#pragma unroll
        for (int k = 0; k < 6; ++k) {
            const uint32_t re = (uint32_t)(OFFS[2*k]   + sidx[2*k])   * (uint32_t)D_DIM;
            const uint32_t ro = (uint32_t)(OFFS[2*k+1] + sidx[2*k+1]) * (uint32_t)D_DIM;
            voff[k] = (hi ? ro : re) + (uint32_t)d0;     // 1 cndmask + 1 add
            const float fe = (sidx[2*k]   != 0) ? 1.f : 0.f;  // scalar
            const float fo = (sidx[2*k+1] != 0) ? 1.f : 0.f;  // scalar
            fmask[k] = hi ? fo : fe;                     // 1 cndmask
        }

        // --- issue all 6 independent table gathers (SGPR base + u32 voffset) ---
        f32x4 v[6];
#pragma unroll
        for (int k = 0; k < 6; ++k)
            v[k] = *reinterpret_cast<const f32x4*>(table + voff[k]);

        // --- cont rows 12..15: x*w + b (pure VALU, overlaps gather latency) ---
        f32x4 rc[2];
#pragma unroll
        for (int k = 0; k < 2; ++k) {
            const float x = hi ? sx[2*k+1] : sx[2*k];
            rc[k].x = fmaf(x, wv[k].x, bv[k].x);
            rc[k].y = fmaf(x, wv[k].y, bv[k].y);
            rc[k].z = fmaf(x, wv[k].z, bv[k].z);
            rc[k].w = fmaf(x, wv[k].w, bv[k].w);
        }

        float* outp = out + (size_t)token * (SLOTS * D_DIM) + hi * D_DIM + d0;

        // --- prefetch NEXT token's scalars while gathers are in flight ---
        const int  next = token + nwaves;
        const bool more = next < n_tok;
        if (more) load_scalars(next);

        // --- padding zeroing + 8 nontemporal stores (wave: 8 KB contiguous) ---
#pragma unroll
        for (int k = 0; k < 6; ++k) {
            f32x4 r = v[k];
            r.x *= fmask[k]; r.y *= fmask[k]; r.z *= fmask[k]; r.w *= fmask[k];
            __builtin_nontemporal_store(
                r, reinterpret_cast<f32x4*>(outp + k * (2 * D_DIM)));
        }
#pragma unroll
        for (int k = 0; k < 2; ++k)
            __builtin_nontemporal_store(
                rc[k], reinterpret_cast<f32x4*>(outp + (C_FIELDS + 2 * k) * D_DIM));

        if (!more) break;
        token = next;
    }
}

extern "C" void kernel_launch(void* const* d_in, const int* in_sizes, int n_in,
                              void* d_out, int out_size, void* d_ws, size_t ws_size,
                              hipStream_t stream) {
    const int*   cat   = (const int*)d_in[0];
    const float* cont  = (const float*)d_in[1];
    const float* table = (const float*)d_in[2];
    const float* wc    = (const float*)d_in[3];
    const float* bc    = (const float*)d_in[4];
    float*       out   = (float*)d_out;

    const int n_tok = in_sizes[0] / C_FIELDS;    // B*L = 32768

    // Persistent waves: 2048 blocks x 4 waves = 8192 waves = 32 waves/CU on
    // 256 CUs (full residency at <=64 VGPR); each wave handles
    // ceil(n_tok/8192) tokens (4 at the bench shape).
    const int block = 256;
    int grid = (n_tok + 3) / 4;                  // waves needed / 4 per block
    if (grid > 2048) grid = 2048;
    if (grid < 1)    grid = 1;

    emb_fused_kernel<<<grid, block, 0, stream>>>(cat, cont, table, wc, bc, out, n_tok);
}

// Round 4
// 347.504 us; speedup vs baseline: 1.0203x; 1.0113x over previous
//
#include <hip/hip_runtime.h>

// Problem constants (from reference)
#define C_FIELDS 12
#define F_FIELDS 4
#define SLOTS    16      // C + F
#define D_DIM    128

using f32x4 = __attribute__((ext_vector_type(4))) float;

// One WAVE per token, PERSISTENT waves (grid = 2048 blocks = 32 waves/CU),
// 4 tokens per wave at NTOK=32768.
//
// R3 A/B: identical to the previous round EXCEPT nontemporal stores ->
// PLAIN stores. Rationale: across three structurally different kernels
// (MLP=1 naive / MLP=6 wave-per-token / persistent+scalar-prefetch) the
// kernel-side time was invariant (~185/183/178 us), i.e. capped by a shared
// throughput resource. All three used __builtin_nontemporal_store for the
// 268 MB output stream, achieving only ~1.5 TB/s effective -- while the
// harness's own fillBufferAligned writes 1.07 GB with PLAIN stores at
// 6.26 TB/s in the same graph. Theory: the gfx950 `nt` store path caps the
// write stream; the L3-protection argument for NT is moot because the
// 1.07 GB per-iteration poison flushes L2/L3 anyway (table is cold each
// run; unique gathered rows are only ~29 MB vs 256 MB L3).
__global__ __launch_bounds__(256) void emb_fused_kernel(
    const int*   __restrict__ cat,     // [NTOK, 12] int32
    const float* __restrict__ cont,    // [NTOK, 4]
    const float* __restrict__ table,   // [V_TOTAL, 128]
    const float* __restrict__ wc,      // [4, 128]
    const float* __restrict__ bc,      // [4, 128]
    float*       __restrict__ out,     // [NTOK*16, 128]
    int n_tok)
{
    // Exclusive prefix sums of VOCABS {100000,800,200,5000,60,30000,10,8,50,2000,20,16}
    constexpr int OFFS[C_FIELDS] = {
        0, 100000, 100800, 101000, 106000, 106060,
        136060, 136070, 136078, 136128, 138128, 138148
    };

    const int lane = threadIdx.x & 63;
    const int hi   = lane >> 5;                  // row parity within pair
    const int d0   = (lane & 31) << 2;           // fp32 element offset in D

    // wave id is uniform; pin to SGPR so per-token index/cont loads
    // scalarize to s_load.
    const int wave0  = __builtin_amdgcn_readfirstlane(
        (int)((blockIdx.x * blockDim.x + threadIdx.x) >> 6));
    const int nwaves = (int)((gridDim.x * blockDim.x) >> 6);

    // --- loop-invariant cont-field weights: rows 12+2k+hi use field 2k+hi ---
    f32x4 wv[2], bv[2];
#pragma unroll
    for (int k = 0; k < 2; ++k) {
        const int f = 2 * k + hi;
        wv[k] = *reinterpret_cast<const f32x4*>(wc + f * D_DIM + d0);
        bv[k] = *reinterpret_cast<const f32x4*>(bc + f * D_DIM + d0);
    }

    int   sidx[C_FIELDS];
    float sx[F_FIELDS];
    auto load_scalars = [&](int token) {
        const int*   catrow  = cat  + token * C_FIELDS;   // uniform -> s_load
        const float* controw = cont + token * F_FIELDS;
#pragma unroll
        for (int c = 0; c < C_FIELDS; ++c) sidx[c] = catrow[c];
#pragma unroll
        for (int f = 0; f < F_FIELDS; ++f) sx[f] = controw[f];
    };

    int token = wave0;
    if (token >= n_tok) return;
    load_scalars(token);

    while (true) {
        // per-lane gather offsets (fp32-element units) + padding masks
        uint32_t voff[6];
        float    fmask[6];
#pragma unroll
        for (int k = 0; k < 6; ++k) {
            const uint32_t re = (uint32_t)(OFFS[2*k]   + sidx[2*k])   * (uint32_t)D_DIM;
            const uint32_t ro = (uint32_t)(OFFS[2*k+1] + sidx[2*k+1]) * (uint32_t)D_DIM;
            voff[k] = (hi ? ro : re) + (uint32_t)d0;     // 1 cndmask + 1 add
            const float fe = (sidx[2*k]   != 0) ? 1.f : 0.f;  // scalar
            const float fo = (sidx[2*k+1] != 0) ? 1.f : 0.f;  // scalar
            fmask[k] = hi ? fo : fe;                     // 1 cndmask
        }

        // --- issue all 6 independent table gathers (SGPR base + u32 voffset) ---
        f32x4 v[6];
#pragma unroll
        for (int k = 0; k < 6; ++k)
            v[k] = *reinterpret_cast<const f32x4*>(table + voff[k]);

        // --- cont rows 12..15: x*w + b (pure VALU, overlaps gather latency) ---
        f32x4 rc[2];
#pragma unroll
        for (int k = 0; k < 2; ++k) {
            const float x = hi ? sx[2*k+1] : sx[2*k];
            rc[k].x = fmaf(x, wv[k].x, bv[k].x);
            rc[k].y = fmaf(x, wv[k].y, bv[k].y);
            rc[k].z = fmaf(x, wv[k].z, bv[k].z);
            rc[k].w = fmaf(x, wv[k].w, bv[k].w);
        }

        float* outp = out + (size_t)token * (SLOTS * D_DIM) + hi * D_DIM + d0;

        // --- prefetch NEXT token's scalars while gathers are in flight ---
        const int  next = token + nwaves;
        const bool more = next < n_tok;
        if (more) load_scalars(next);

        // --- padding zeroing + 8 PLAIN stores (wave: 8 KB contiguous) ---
#pragma unroll
        for (int k = 0; k < 6; ++k) {
            f32x4 r = v[k];
            r.x *= fmask[k]; r.y *= fmask[k]; r.z *= fmask[k]; r.w *= fmask[k];
            *reinterpret_cast<f32x4*>(outp + k * (2 * D_DIM)) = r;
        }
#pragma unroll
        for (int k = 0; k < 2; ++k)
            *reinterpret_cast<f32x4*>(outp + (C_FIELDS + 2 * k) * D_DIM) = rc[k];

        if (!more) break;
        token = next;
    }
}

extern "C" void kernel_launch(void* const* d_in, const int* in_sizes, int n_in,
                              void* d_out, int out_size, void* d_ws, size_t ws_size,
                              hipStream_t stream) {
    const int*   cat   = (const int*)d_in[0];
    const float* cont  = (const float*)d_in[1];
    const float* table = (const float*)d_in[2];
    const float* wc    = (const float*)d_in[3];
    const float* bc    = (const float*)d_in[4];
    float*       out   = (float*)d_out;

    const int n_tok = in_sizes[0] / C_FIELDS;    // B*L = 32768

    // Persistent waves: 2048 blocks x 4 waves = 8192 waves = 32 waves/CU on
    // 256 CUs; each wave handles ceil(n_tok/8192) tokens (4 at bench shape).
    const int block = 256;
    int grid = (n_tok + 3) / 4;
    if (grid > 2048) grid = 2048;
    if (grid < 1)    grid = 1;

    emb_fused_kernel<<<grid, block, 0, stream>>>(cat, cont, table, wc, bc, out, n_tok);
}